// Round 2
// baseline (261.348 us; speedup 1.0000x reference)
//
#include <hip/hip_runtime.h>
#include <hip/hip_bf16.h>

typedef __hip_bfloat16 bf16;
typedef __attribute__((ext_vector_type(8))) short short8;
typedef __attribute__((ext_vector_type(4))) float f32x4;

#define SS 512
#define HD 768
#define NEGC (-1e30f)

// ---------------------------------------------------------------------------
// Convert the 6 GEMM weight matrices f32 -> bf16 into one contiguous ws blob.
// Offsets (bf16 elems): ner_rep_w@0(1204224) emd_rep_w@1204224
//   rel_w1@2408448(1818624) cr_w1@4227072 rel_w2@6045696(589824) cr_w2@6635520
// total 7225344. grid 7056 x 256, 4 elems/thread (float4 load).
// ---------------------------------------------------------------------------
#define WOFF_NER 0
#define WOFF_EMD 1204224
#define WOFF_RW1 2408448
#define WOFF_CW1 4227072
#define WOFF_RW2 6045696
#define WOFF_CW2 6635520
#define W_TOT    7225344

__global__ __launch_bounds__(256) void k_cvtw(
    const float* __restrict__ s0, const float* __restrict__ s1,
    const float* __restrict__ s2, const float* __restrict__ s3,
    const float* __restrict__ s4, const float* __restrict__ s5,
    bf16* __restrict__ dst)
{
  size_t i = ((size_t)blockIdx.x * 256 + threadIdx.x) * 4;
  if (i >= W_TOT) return;
  const float* s; size_t off;
  if      (i < WOFF_EMD) { s = s0; off = i; }
  else if (i < WOFF_RW1) { s = s1; off = i - WOFF_EMD; }
  else if (i < WOFF_CW1) { s = s2; off = i - WOFF_RW1; }
  else if (i < WOFF_RW2) { s = s3; off = i - WOFF_CW1; }
  else if (i < WOFF_CW2) { s = s4; off = i - WOFF_RW2; }
  else                   { s = s5; off = i - WOFF_CW2; }
  float4 v = *(const float4*)(s + off);
  dst[i]     = __hip_bfloat16(v.x);
  dst[i + 1] = __hip_bfloat16(v.y);
  dst[i + 2] = __hip_bfloat16(v.z);
  dst[i + 3] = __hip_bfloat16(v.w);
}

// ---------------------------------------------------------------------------
// Pooling: grid (48 groups, B=2, 4 S-splits), block 256.
// Each block: 8 spans, 128 tokens, all 768 h. Partials stored bf16
// (max commutes with monotone rounding -> no extra error).
// Unified span index j in [0,384): [0,64) entity, [64,128) mention,
// [128,256) rel, [256,384) ref. part[split][b*384+j][h].
// ---------------------------------------------------------------------------
__global__ __launch_bounds__(256) void k_pool(
    const int* __restrict__ e_masks, const int* __restrict__ m_masks,
    const int* __restrict__ r_masks, const int* __restrict__ c_masks,
    const float* __restrict__ emb, bf16* __restrict__ part, int* __restrict__ flags)
{
  int g  = blockIdx.x;        // 0..47
  int b  = blockIdx.y;        // 0..1
  int sp = blockIdx.z;        // 0..3
  int j0 = g * 8;

  const int* marr; int row0;
  if      (j0 < 64)  { marr = e_masks; row0 = b*64  +  j0;        }
  else if (j0 < 128) { marr = m_masks; row0 = b*64  + (j0-64);    }
  else if (j0 < 256) { marr = r_masks; row0 = b*128 + (j0-128);   }
  else               { marr = c_masks; row0 = b*128 + (j0-256);   }

  __shared__ unsigned s_pack[128];
  __shared__ unsigned s_any;
  int t = threadIdx.x;
  if (t == 0) s_any = 0u;
  __syncthreads();

  int sbase = sp * 128;
  if (t < 128) {
    unsigned w = 0;
    #pragma unroll
    for (int k = 0; k < 8; k++) {
      int mm = marr[(size_t)(row0 + k) * SS + sbase + t];
      w |= (mm != 0 ? 1u : 0u) << k;
    }
    s_pack[t] = w;
    atomicOr(&s_any, w);
  }
  __syncthreads();

  float acc[8][3];
  #pragma unroll
  for (int k = 0; k < 8; k++)
    #pragma unroll
    for (int i = 0; i < 3; i++) acc[k][i] = -INFINITY;

  const float* ebase = emb + ((size_t)b * SS + sbase) * HD;
  for (int s = 0; s < 128; s++) {
    unsigned wm = s_pack[s];
    const float* ep = ebase + (size_t)s * HD + t;
    float v0 = ep[0];
    float v1 = ep[256];
    float v2 = ep[512];
    #pragma unroll
    for (int k = 0; k < 8; k++) {
      float add = ((wm >> k) & 1u) ? 0.f : NEGC;
      acc[k][0] = fmaxf(acc[k][0], v0 + add);
      acc[k][1] = fmaxf(acc[k][1], v1 + add);
      acc[k][2] = fmaxf(acc[k][2], v2 + add);
    }
  }

  #pragma unroll
  for (int k = 0; k < 8; k++) {
    int sg = b * 384 + j0 + k;
    bf16* dst = part + ((size_t)sp * 768 + sg) * HD;
    dst[t]       = __hip_bfloat16(acc[k][0]);
    dst[t + 256] = __hip_bfloat16(acc[k][1]);
    dst[t + 512] = __hip_bfloat16(acc[k][2]);
  }
  if (t < 8) flags[sp * 768 + b * 384 + j0 + t] = (int)((s_any >> t) & 1u);
}

// ---------------------------------------------------------------------------
// Combine the 4 S-split partials; write bf16 pools / ctx buffers.
// grid 768 (span-global), block 256 (3 h each).
// ---------------------------------------------------------------------------
__global__ __launch_bounds__(256) void k_combine(
    const bf16* __restrict__ part, const int* __restrict__ flags,
    bf16* __restrict__ epool, bf16* __restrict__ mpool,
    bf16* __restrict__ rctx, bf16* __restrict__ cctx)
{
  int sg = blockIdx.x;
  int b = sg / 384, j = sg % 384;
  int any = flags[sg] | flags[768 + sg] | flags[1536 + sg] | flags[2304 + sg];
  #pragma unroll
  for (int i = 0; i < 3; i++) {
    int h = threadIdx.x + i * 256;
    float v = (float)part[(size_t)sg * HD + h];
    v = fmaxf(v, (float)part[(size_t)(768  + sg) * HD + h]);
    v = fmaxf(v, (float)part[(size_t)(1536 + sg) * HD + h]);
    v = fmaxf(v, (float)part[(size_t)(2304 + sg) * HD + h]);
    if      (j < 64)  epool[((size_t)b*64  + j)       * HD + h] = __hip_bfloat16(v);
    else if (j < 128) mpool[((size_t)b*64  + (j-64))  * HD + h] = __hip_bfloat16(v);
    else if (j < 256) rctx [((size_t)b*128 + (j-128)) * HD + h] = __hip_bfloat16(any ? v : 0.f);
    else              cctx [((size_t)b*128 + (j-256)) * HD + h] = __hip_bfloat16(any ? v : 0.f);
  }
}

// ---------------------------------------------------------------------------
// Span rep build: rep = [ctx(cls) 768 | pool 768 | size_emb 32]  (1568)
// grid (128 rows, 2 which), block 256. which: 0=ner(entity) 1=emd(mention)
// ---------------------------------------------------------------------------
__global__ __launch_bounds__(256) void k_rep_span(
    const int* __restrict__ input_ids, const float* __restrict__ emb,
    const bf16* __restrict__ epool, const bf16* __restrict__ mpool,
    const int* __restrict__ esizes, const int* __restrict__ msizes,
    const float* __restrict__ nsemb, const float* __restrict__ esemb,
    bf16* __restrict__ nrep, bf16* __restrict__ erep)
{
  int which = blockIdx.y;
  int row = blockIdx.x;           // b*64 + e
  int b = row >> 6;
  const bf16*  pool  = which ? mpool  : epool;
  const int*   sizes = which ? msizes : esizes;
  const float* st    = which ? esemb  : nsemb;
  bf16* rep = (which ? erep : nrep) + (size_t)row * 1568;

  __shared__ int s_cls;
  if (threadIdx.x == 0) s_cls = SS;
  __syncthreads();
  for (int s = threadIdx.x; s < SS; s += 256)
    if (input_ids[b * SS + s] == 101) atomicMin(&s_cls, s);
  __syncthreads();
  int ci = (s_cls == SS) ? 0 : s_cls;

  const float* ctx = emb + ((size_t)b * SS + ci) * HD;
  const bf16*  pl  = pool + (size_t)row * HD;
  for (int h = threadIdx.x; h < HD; h += 256) {
    rep[h]       = __hip_bfloat16(ctx[h]);
    rep[768 + h] = pl[h];
  }
  if (threadIdx.x < 32)
    rep[1536 + threadIdx.x] = __hip_bfloat16(st[(size_t)sizes[row] * 32 + threadIdx.x]);
}

// ---------------------------------------------------------------------------
// Relation rep build: rep = [ctx 768 | pool[a0] 768 | pool[a1] 768 | sz0 32 | sz1 32]
// grid (256 rows, 2 which), block 256. which: 0=rel 1=cr
// ---------------------------------------------------------------------------
__global__ __launch_bounds__(256) void k_rep_rel(
    const int* __restrict__ relations, const int* __restrict__ references,
    const bf16* __restrict__ rctx, const bf16* __restrict__ cctx,
    const bf16* __restrict__ epool, const bf16* __restrict__ mpool,
    const int* __restrict__ esizes, const int* __restrict__ msizes,
    const float* __restrict__ nsemb, const float* __restrict__ esemb,
    bf16* __restrict__ rrep, bf16* __restrict__ crep)
{
  int which = blockIdx.y;
  int row = blockIdx.x;           // b*128 + r
  int b = row >> 7;
  const int*   rel   = which ? references : relations;
  const bf16*  ctx   = which ? cctx   : rctx;
  const bf16*  pool  = which ? mpool  : epool;
  const int*   sizes = which ? msizes : esizes;
  const float* st    = which ? esemb  : nsemb;
  bf16* rep = (which ? crep : rrep) + (size_t)row * 2368;

  int a0 = rel[row * 2], a1 = rel[row * 2 + 1];
  const bf16* p0 = pool + ((size_t)b * 64 + a0) * HD;
  const bf16* p1 = pool + ((size_t)b * 64 + a1) * HD;
  const bf16* cx = ctx + (size_t)row * HD;
  for (int h = threadIdx.x; h < HD; h += 256) {
    rep[h]        = cx[h];
    rep[768 + h]  = p0[h];
    rep[1536 + h] = p1[h];
  }
  if (threadIdx.x < 32) {
    rep[2304 + threadIdx.x] = __hip_bfloat16(st[(size_t)sizes[b * 64 + a0] * 32 + threadIdx.x]);
    rep[2336 + threadIdx.x] = __hip_bfloat16(st[(size_t)sizes[b * 64 + a1] * 32 + threadIdx.x]);
  }
}

// ---------------------------------------------------------------------------
// Mid GEMM: C[M,768] = relu(A[M,K] @ W[768,K]^T + bias). MFMA 16x16x32 bf16,
// one wave per 32x32 tile. grid (M/32, 24, 2-problems), block 64.
// A,W bf16; bias f32; C f32 or bf16.
// ---------------------------------------------------------------------------
__global__ __launch_bounds__(64) void k_gemm(
    const void* A0_, const void* A1_, const void* W0_, const void* W1_,
    const float* b0_, const float* b1_, void* C0_, void* C1_,
    int K_, int store_bf16)
{
  int pz = blockIdx.z;
  const short* A = (const short*)(pz ? A1_ : A0_);
  const short* W = (const short*)(pz ? W1_ : W0_);
  const float* bias = pz ? b1_ : b0_;
  void* Cv = pz ? C1_ : C0_;

  int lane = threadIdx.x;
  int lm = lane & 15, quad = lane >> 4;
  int mt = blockIdx.x * 32, nt = blockIdx.y * 32;

  const short* a0p = A + (size_t)(mt + lm)      * K_ + quad * 8;
  const short* a1p = A + (size_t)(mt + 16 + lm) * K_ + quad * 8;
  const short* w0p = W + (size_t)(nt + lm)      * K_ + quad * 8;
  const short* w1p = W + (size_t)(nt + 16 + lm) * K_ + quad * 8;

  f32x4 acc00 = {0.f,0.f,0.f,0.f}, acc01 = {0.f,0.f,0.f,0.f};
  f32x4 acc10 = {0.f,0.f,0.f,0.f}, acc11 = {0.f,0.f,0.f,0.f};

  for (int k0 = 0; k0 < K_; k0 += 32) {
    short8 a0 = *(const short8*)(a0p + k0);
    short8 a1 = *(const short8*)(a1p + k0);
    short8 w0 = *(const short8*)(w0p + k0);
    short8 w1 = *(const short8*)(w1p + k0);
    acc00 = __builtin_amdgcn_mfma_f32_16x16x32_bf16(a0, w0, acc00, 0, 0, 0);
    acc01 = __builtin_amdgcn_mfma_f32_16x16x32_bf16(a0, w1, acc01, 0, 0, 0);
    acc10 = __builtin_amdgcn_mfma_f32_16x16x32_bf16(a1, w0, acc10, 0, 0, 0);
    acc11 = __builtin_amdgcn_mfma_f32_16x16x32_bf16(a1, w1, acc11, 0, 0, 0);
  }

  int col0 = nt + lm, col1 = nt + 16 + lm;
  float bb0 = bias[col0], bb1 = bias[col1];
  #pragma unroll
  for (int reg = 0; reg < 4; reg++) {
    int r0 = mt + quad * 4 + reg;
    int r1 = r0 + 16;
    float v00 = fmaxf(acc00[reg] + bb0, 0.f);
    float v01 = fmaxf(acc01[reg] + bb1, 0.f);
    float v10 = fmaxf(acc10[reg] + bb0, 0.f);
    float v11 = fmaxf(acc11[reg] + bb1, 0.f);
    if (store_bf16) {
      bf16* C = (bf16*)Cv;
      C[(size_t)r0 * HD + col0] = __hip_bfloat16(v00);
      C[(size_t)r0 * HD + col1] = __hip_bfloat16(v01);
      C[(size_t)r1 * HD + col0] = __hip_bfloat16(v10);
      C[(size_t)r1 * HD + col1] = __hip_bfloat16(v11);
    } else {
      float* C = (float*)Cv;
      C[(size_t)r0 * HD + col0] = v00;
      C[(size_t)r0 * HD + col1] = v01;
      C[(size_t)r1 * HD + col0] = v10;
      C[(size_t)r1 * HD + col1] = v11;
    }
  }
}

// ---------------------------------------------------------------------------
// Heads: all 4 output projections (f32 weights/act), one row per block.
// grid 768: [0,128) ner N=10 | [128,384) rel N=8 | [384,512) emd N=2 | [512,768) cr N=1
// ---------------------------------------------------------------------------
__global__ __launch_bounds__(256) void k_heads(
    const float* __restrict__ NH, const float* __restrict__ EH,
    const float* __restrict__ RH2, const float* __restrict__ CH2,
    const float* __restrict__ nhw, const float* __restrict__ nhb,
    const float* __restrict__ ehw, const float* __restrict__ ehb,
    const float* __restrict__ rw3, const float* __restrict__ rb3,
    const float* __restrict__ cw3, const float* __restrict__ cb3,
    float* __restrict__ out)
{
  int gr = blockIdx.x;
  const float* A; const float* W; const float* Bb; float* op; int N;
  if (gr < 128)      { A = NH  + (size_t)gr * HD;        W = nhw; Bb = nhb; N = 10; op = out + (size_t)gr * 10; }
  else if (gr < 384) { int r = gr - 128; A = RH2 + (size_t)r * HD; W = rw3; Bb = rb3; N = 8; op = out + 1280 + (size_t)r * 8; }
  else if (gr < 512) { int r = gr - 384; A = EH  + (size_t)r * HD; W = ehw; Bb = ehb; N = 2; op = out + 3328 + (size_t)r * 2; }
  else               { int r = gr - 512; A = CH2 + (size_t)r * HD; W = cw3; Bb = cb3; N = 1; op = out + 3584 + (size_t)r; }

  float acc[10];
  #pragma unroll
  for (int o = 0; o < 10; o++) acc[o] = 0.f;

  for (int k = threadIdx.x; k < HD; k += 256) {
    float a = A[k];
    #pragma unroll
    for (int o = 0; o < 10; o++) {
      int oo = (o < N) ? o : 0;   // guard OOB weight reads; junk accs unused
      acc[o] += a * W[(size_t)oo * HD + k];
    }
  }

  __shared__ float red[4][10];
  int lane = threadIdx.x & 63, wv = threadIdx.x >> 6;
  #pragma unroll
  for (int o = 0; o < 10; o++) {
    float v = acc[o];
    for (int off = 32; off > 0; off >>= 1) v += __shfl_down(v, off);
    if (lane == 0) red[wv][o] = v;
  }
  __syncthreads();
  if (threadIdx.x < N) {
    float v = red[0][threadIdx.x] + red[1][threadIdx.x] + red[2][threadIdx.x] +
              red[3][threadIdx.x] + Bb[threadIdx.x];
    op[threadIdx.x] = v;
  }
}

// ---------------------------------------------------------------------------
extern "C" void kernel_launch(void* const* d_in, const int* in_sizes, int n_in,
                              void* d_out, int out_size, void* d_ws, size_t ws_size,
                              hipStream_t stream)
{
  const int*   input_ids  = (const int*)d_in[0];
  const int*   e_masks    = (const int*)d_in[1];
  const int*   e_sizes    = (const int*)d_in[2];
  const int*   m_masks    = (const int*)d_in[3];
  const int*   m_sizes    = (const int*)d_in[4];
  const int*   relations  = (const int*)d_in[5];
  const int*   r_masks    = (const int*)d_in[6];
  const int*   references = (const int*)d_in[7];
  const int*   c_masks    = (const int*)d_in[8];
  const float* emb        = (const float*)d_in[9];
  const float* nsemb      = (const float*)d_in[10];
  const float* esemb      = (const float*)d_in[11];
  const float* ner_rep_w  = (const float*)d_in[12];
  const float* ner_rep_b  = (const float*)d_in[13];
  const float* ner_head_w = (const float*)d_in[14];
  const float* ner_head_b = (const float*)d_in[15];
  const float* emd_rep_w  = (const float*)d_in[16];
  const float* emd_rep_b  = (const float*)d_in[17];
  const float* emd_head_w = (const float*)d_in[18];
  const float* emd_head_b = (const float*)d_in[19];
  const float* rel_w1 = (const float*)d_in[20];
  const float* rel_b1 = (const float*)d_in[21];
  const float* rel_w2 = (const float*)d_in[22];
  const float* rel_b2 = (const float*)d_in[23];
  const float* rel_w3 = (const float*)d_in[24];
  const float* rel_b3 = (const float*)d_in[25];
  const float* cr_w1 = (const float*)d_in[26];
  const float* cr_b1 = (const float*)d_in[27];
  const float* cr_w2 = (const float*)d_in[28];
  const float* cr_b2 = (const float*)d_in[29];
  const float* cr_w3 = (const float*)d_in[30];
  const float* cr_b3 = (const float*)d_in[31];
  float* out = (float*)d_out;

  // ---- workspace carve: f32/int region, then bf16 region ----
  float* wsf = (float*)d_ws;
  size_t o = 0;
  int*   FLAGS = (int*)(wsf + o); o += 4 * 768;        // 3072
  float* NH  = wsf + o; o += (size_t)128 * HD;
  float* EH  = wsf + o; o += (size_t)128 * HD;
  float* RH2 = wsf + o; o += (size_t)256 * HD;
  float* CH2 = wsf + o; o += (size_t)256 * HD;

  bf16* wsb = (bf16*)(wsf + o);
  size_t ob = 0;
  bf16* WBF   = wsb + ob; ob += (size_t)W_TOT;          // 7225344
  bf16* PART  = wsb + ob; ob += (size_t)4 * 768 * HD;   // 2359296
  bf16* EPOOL = wsb + ob; ob += (size_t)128 * HD;
  bf16* MPOOL = wsb + ob; ob += (size_t)128 * HD;
  bf16* RCTX  = wsb + ob; ob += (size_t)256 * HD;
  bf16* CCTX  = wsb + ob; ob += (size_t)256 * HD;
  bf16* NREP  = wsb + ob; ob += (size_t)128 * 1568;
  bf16* EREP  = wsb + ob; ob += (size_t)128 * 1568;
  bf16* RREP  = wsb + ob; ob += (size_t)256 * 2368;
  bf16* CREP  = wsb + ob; ob += (size_t)256 * 2368;
  bf16* RH1   = wsb + ob; ob += (size_t)256 * HD;
  bf16* CH1   = wsb + ob; ob += (size_t)256 * HD;

  // 0) weight conversion f32->bf16
  k_cvtw<<<W_TOT / 4 / 256, 256, 0, stream>>>(ner_rep_w, emd_rep_w, rel_w1, cr_w1,
                                              rel_w2, cr_w2, WBF);
  // 1) pooling partials
  k_pool<<<dim3(48, 2, 4), 256, 0, stream>>>(e_masks, m_masks, r_masks, c_masks,
                                             emb, PART, FLAGS);
  // 2) combine splits -> bf16 pools/ctx
  k_combine<<<768, 256, 0, stream>>>(PART, FLAGS, EPOOL, MPOOL, RCTX, CCTX);
  // 3) rep builds
  k_rep_span<<<dim3(128, 2), 256, 0, stream>>>(input_ids, emb, EPOOL, MPOOL,
                                               e_sizes, m_sizes, nsemb, esemb,
                                               NREP, EREP);
  k_rep_rel<<<dim3(256, 2), 256, 0, stream>>>(relations, references, RCTX, CCTX,
                                              EPOOL, MPOOL, e_sizes, m_sizes,
                                              nsemb, esemb, RREP, CREP);
  // 4) GEMM chain
  //    ner1 + emd1: [128,1568] -> [128,768] f32 (relu)
  k_gemm<<<dim3(4, 24, 2), 64, 0, stream>>>(NREP, EREP, WBF + WOFF_NER, WBF + WOFF_EMD,
                                            ner_rep_b, emd_rep_b, NH, EH, 1568, 0);
  //    rel1 + cr1: [256,2368] -> [256,768] bf16 (relu)
  k_gemm<<<dim3(8, 24, 2), 64, 0, stream>>>(RREP, CREP, WBF + WOFF_RW1, WBF + WOFF_CW1,
                                            rel_b1, cr_b1, RH1, CH1, 2368, 1);
  //    rel2 + cr2: [256,768] -> [256,768] f32 (relu)
  k_gemm<<<dim3(8, 24, 2), 64, 0, stream>>>(RH1, CH1, WBF + WOFF_RW2, WBF + WOFF_CW2,
                                            rel_b2, cr_b2, RH2, CH2, 768, 0);
  // 5) heads -> d_out
  k_heads<<<768, 256, 0, stream>>>(NH, EH, RH2, CH2,
                                   ner_head_w, ner_head_b, emd_head_w, emd_head_b,
                                   rel_w3, rel_b3, cr_w3, cr_b3, out);
}

// Round 3
// 209.162 us; speedup vs baseline: 1.2495x; 1.2495x over previous
//
#include <hip/hip_runtime.h>
#include <hip/hip_bf16.h>

typedef __hip_bfloat16 bf16;
typedef __attribute__((ext_vector_type(8))) short short8;
typedef __attribute__((ext_vector_type(4))) float f32x4;

#define SS 512
#define HD 768
#define NEGC (-1e30f)

// bf16 weight blob offsets (elements)
#define WOFF_NER 0
#define WOFF_EMD 1204224
#define WOFF_RW1 2408448
#define WOFF_CW1 4227072
#define WOFF_RW2 6045696
#define WOFF_CW2 6635520
#define W_TOT    7225344
#define CVT_BLOCKS (W_TOT / 4 / 256)   // 7056

// ---------------------------------------------------------------------------
// Fused pool + weight-convert dispatch.
// bx < 768: pooling block. 48 span-groups x 2 b x 8 S-splits; 8 spans/block,
//           64 tokens, all 768 h (3/thread). Partials bf16 (max commutes with
//           monotone rounding).
// bx >= 768: weight f32->bf16 convert (1024 elems/block).
// Co-schedules HBM-bound convert with VALU/latency-bound pooling.
// ---------------------------------------------------------------------------
__global__ __launch_bounds__(256) void k_pool_cvt(
    const int* __restrict__ e_masks, const int* __restrict__ m_masks,
    const int* __restrict__ r_masks, const int* __restrict__ c_masks,
    const float* __restrict__ emb, bf16* __restrict__ part, int* __restrict__ flags,
    const float* __restrict__ s0, const float* __restrict__ s1,
    const float* __restrict__ s2, const float* __restrict__ s3,
    const float* __restrict__ s4, const float* __restrict__ s5,
    bf16* __restrict__ wdst)
{
  int bx = blockIdx.x;
  int t  = threadIdx.x;

  if (bx >= 768) {
    // ---- weight convert ----
    size_t i = ((size_t)(bx - 768) * 256 + t) * 4;
    const float* s; size_t off;
    if      (i < WOFF_EMD) { s = s0; off = i; }
    else if (i < WOFF_RW1) { s = s1; off = i - WOFF_EMD; }
    else if (i < WOFF_CW1) { s = s2; off = i - WOFF_RW1; }
    else if (i < WOFF_RW2) { s = s3; off = i - WOFF_CW1; }
    else if (i < WOFF_CW2) { s = s4; off = i - WOFF_RW2; }
    else                   { s = s5; off = i - WOFF_CW2; }
    float4 v = *(const float4*)(s + off);
    wdst[i]     = __hip_bfloat16(v.x);
    wdst[i + 1] = __hip_bfloat16(v.y);
    wdst[i + 2] = __hip_bfloat16(v.z);
    wdst[i + 3] = __hip_bfloat16(v.w);
    return;
  }

  // ---- pooling ----
  int g  = bx % 48;            // span group (8 spans)
  int b  = (bx / 48) & 1;      // batch
  int sp = bx / 96;            // S-split 0..7 (64 tokens each)
  int j0 = g * 8;

  const int* marr; int row0;
  if      (j0 < 64)  { marr = e_masks; row0 = b*64  +  j0;        }
  else if (j0 < 128) { marr = m_masks; row0 = b*64  + (j0-64);    }
  else if (j0 < 256) { marr = r_masks; row0 = b*128 + (j0-128);   }
  else               { marr = c_masks; row0 = b*128 + (j0-256);   }

  __shared__ unsigned s_pack[64];
  __shared__ unsigned s_any;
  if (t == 0) s_any = 0u;
  __syncthreads();

  int sbase = sp * 64;
  if (t < 64) {
    unsigned w = 0;
    #pragma unroll
    for (int k = 0; k < 8; k++) {
      int mm = marr[(size_t)(row0 + k) * SS + sbase + t];
      w |= (mm != 0 ? 1u : 0u) << k;
    }
    s_pack[t] = w;
    atomicOr(&s_any, w);
  }
  __syncthreads();

  float acc[8][3];
  #pragma unroll
  for (int k = 0; k < 8; k++)
    #pragma unroll
    for (int i = 0; i < 3; i++) acc[k][i] = -INFINITY;

  const float* ebase = emb + ((size_t)b * SS + sbase) * HD;
  for (int s = 0; s < 64; s++) {
    unsigned wm = s_pack[s];
    const float* ep = ebase + (size_t)s * HD + t;
    float v0 = ep[0];
    float v1 = ep[256];
    float v2 = ep[512];
    #pragma unroll
    for (int k = 0; k < 8; k++) {
      float add = ((wm >> k) & 1u) ? 0.f : NEGC;
      acc[k][0] = fmaxf(acc[k][0], v0 + add);
      acc[k][1] = fmaxf(acc[k][1], v1 + add);
      acc[k][2] = fmaxf(acc[k][2], v2 + add);
    }
  }

  #pragma unroll
  for (int k = 0; k < 8; k++) {
    int sg = b * 384 + j0 + k;
    bf16* dst = part + ((size_t)sp * 768 + sg) * HD;
    dst[t]       = __hip_bfloat16(acc[k][0]);
    dst[t + 256] = __hip_bfloat16(acc[k][1]);
    dst[t + 512] = __hip_bfloat16(acc[k][2]);
  }
  if (t < 8) flags[sp * 768 + b * 384 + j0 + t] = (int)((s_any >> t) & 1u);
}

// ---------------------------------------------------------------------------
// Combine the 8 S-split partials; write bf16 pools / ctx buffers.
// grid 768 (span-global), block 256 (3 h each).
// ---------------------------------------------------------------------------
__global__ __launch_bounds__(256) void k_combine(
    const bf16* __restrict__ part, const int* __restrict__ flags,
    bf16* __restrict__ epool, bf16* __restrict__ mpool,
    bf16* __restrict__ rctx, bf16* __restrict__ cctx)
{
  int sg = blockIdx.x;
  int b = sg / 384, j = sg % 384;
  int any = 0;
  #pragma unroll
  for (int sp = 0; sp < 8; sp++) any |= flags[sp * 768 + sg];
  #pragma unroll
  for (int i = 0; i < 3; i++) {
    int h = threadIdx.x + i * 256;
    float v = -INFINITY;
    #pragma unroll
    for (int sp = 0; sp < 8; sp++)
      v = fmaxf(v, (float)part[((size_t)sp * 768 + sg) * HD + h]);
    if      (j < 64)  epool[((size_t)b*64  + j)       * HD + h] = __hip_bfloat16(v);
    else if (j < 128) mpool[((size_t)b*64  + (j-64))  * HD + h] = __hip_bfloat16(v);
    else if (j < 256) rctx [((size_t)b*128 + (j-128)) * HD + h] = __hip_bfloat16(any ? v : 0.f);
    else              cctx [((size_t)b*128 + (j-256)) * HD + h] = __hip_bfloat16(any ? v : 0.f);
  }
}

// ---------------------------------------------------------------------------
// Rep builds, merged. grid (256, 4):
//  y=0/1: span reps (ner/emd), rows 0..127 (x>=128 early-exit)
//  y=2/3: relation reps (rel/cr), rows 0..255
// ---------------------------------------------------------------------------
__global__ __launch_bounds__(256) void k_rep(
    const int* __restrict__ input_ids, const float* __restrict__ emb,
    const bf16* __restrict__ epool, const bf16* __restrict__ mpool,
    const bf16* __restrict__ rctx, const bf16* __restrict__ cctx,
    const int* __restrict__ esizes, const int* __restrict__ msizes,
    const float* __restrict__ nsemb, const float* __restrict__ esemb,
    const int* __restrict__ relations, const int* __restrict__ references,
    bf16* __restrict__ nrep, bf16* __restrict__ erep,
    bf16* __restrict__ rrep, bf16* __restrict__ crep)
{
  int mode = blockIdx.y;
  if (mode < 2) {
    if (blockIdx.x >= 128) return;
    int which = mode;
    int row = blockIdx.x;           // b*64 + e
    int b = row >> 6;
    const bf16*  pool  = which ? mpool  : epool;
    const int*   sizes = which ? msizes : esizes;
    const float* st    = which ? esemb  : nsemb;
    bf16* rep = (which ? erep : nrep) + (size_t)row * 1568;

    __shared__ int s_cls;
    if (threadIdx.x == 0) s_cls = SS;
    __syncthreads();
    for (int s = threadIdx.x; s < SS; s += 256)
      if (input_ids[b * SS + s] == 101) atomicMin(&s_cls, s);
    __syncthreads();
    int ci = (s_cls == SS) ? 0 : s_cls;

    const float* ctx = emb + ((size_t)b * SS + ci) * HD;
    const bf16*  pl  = pool + (size_t)row * HD;
    for (int h = threadIdx.x; h < HD; h += 256) {
      rep[h]       = __hip_bfloat16(ctx[h]);
      rep[768 + h] = pl[h];
    }
    if (threadIdx.x < 32)
      rep[1536 + threadIdx.x] = __hip_bfloat16(st[(size_t)sizes[row] * 32 + threadIdx.x]);
  } else {
    int which = mode - 2;
    int row = blockIdx.x;           // b*128 + r
    int b = row >> 7;
    const int*   rel   = which ? references : relations;
    const bf16*  ctx   = which ? cctx   : rctx;
    const bf16*  pool  = which ? mpool  : epool;
    const int*   sizes = which ? msizes : esizes;
    const float* st    = which ? esemb  : nsemb;
    bf16* rep = (which ? crep : rrep) + (size_t)row * 2368;

    int a0 = rel[row * 2], a1 = rel[row * 2 + 1];
    const bf16* p0 = pool + ((size_t)b * 64 + a0) * HD;
    const bf16* p1 = pool + ((size_t)b * 64 + a1) * HD;
    const bf16* cx = ctx + (size_t)row * HD;
    for (int h = threadIdx.x; h < HD; h += 256) {
      rep[h]        = cx[h];
      rep[768 + h]  = p0[h];
      rep[1536 + h] = p1[h];
    }
    if (threadIdx.x < 32) {
      rep[2304 + threadIdx.x] = __hip_bfloat16(st[(size_t)sizes[b * 64 + a0] * 32 + threadIdx.x]);
      rep[2336 + threadIdx.x] = __hip_bfloat16(st[(size_t)sizes[b * 64 + a1] * 32 + threadIdx.x]);
    }
  }
}

// ---------------------------------------------------------------------------
// Batched GEMM: up to 4 problems (grid z). C[M,768]=relu(A[M,K]@W[768,K]^T+b).
// Block 256 = 4 waves; each wave takes K-chunks strided by 128, LDS-reduce,
// then 256 threads do bias+relu+store. MFMA 16x16x32 bf16.
// ---------------------------------------------------------------------------
struct GemmArgs  { const void* A; const void* W; const float* bias; void* C; int K; int M; int store_bf16; };
struct GemmArgs4 { GemmArgs p[4]; };

__global__ __launch_bounds__(256) void k_gemm4(GemmArgs4 ga)
{
  GemmArgs g = ga.p[blockIdx.z];
  int mt = blockIdx.x * 32;
  if (mt >= g.M) return;
  int nt = blockIdx.y * 32;

  const short* A = (const short*)g.A;
  const short* W = (const short*)g.W;
  int K_ = g.K;

  int wave = threadIdx.x >> 6, lane = threadIdx.x & 63;
  int lm = lane & 15, quad = lane >> 4;

  const short* a0p = A + (size_t)(mt + lm)      * K_ + quad * 8;
  const short* a1p = A + (size_t)(mt + 16 + lm) * K_ + quad * 8;
  const short* w0p = W + (size_t)(nt + lm)      * K_ + quad * 8;
  const short* w1p = W + (size_t)(nt + 16 + lm) * K_ + quad * 8;

  f32x4 acc00 = {0.f,0.f,0.f,0.f}, acc01 = {0.f,0.f,0.f,0.f};
  f32x4 acc10 = {0.f,0.f,0.f,0.f}, acc11 = {0.f,0.f,0.f,0.f};

  for (int k0 = wave * 32; k0 < K_; k0 += 128) {
    short8 a0 = *(const short8*)(a0p + k0);
    short8 a1 = *(const short8*)(a1p + k0);
    short8 w0 = *(const short8*)(w0p + k0);
    short8 w1 = *(const short8*)(w1p + k0);
    acc00 = __builtin_amdgcn_mfma_f32_16x16x32_bf16(a0, w0, acc00, 0, 0, 0);
    acc01 = __builtin_amdgcn_mfma_f32_16x16x32_bf16(a0, w1, acc01, 0, 0, 0);
    acc10 = __builtin_amdgcn_mfma_f32_16x16x32_bf16(a1, w0, acc10, 0, 0, 0);
    acc11 = __builtin_amdgcn_mfma_f32_16x16x32_bf16(a1, w1, acc11, 0, 0, 0);
  }

  __shared__ float red[4][32][32];
  #pragma unroll
  for (int reg = 0; reg < 4; reg++) {
    int r = quad * 4 + reg;
    red[wave][r][lm]           = acc00[reg];
    red[wave][r][16 + lm]      = acc01[reg];
    red[wave][16 + r][lm]      = acc10[reg];
    red[wave][16 + r][16 + lm] = acc11[reg];
  }
  __syncthreads();

  int c = threadIdx.x & 31;
  int rb = threadIdx.x >> 5;
  float bb = g.bias[nt + c];
  #pragma unroll
  for (int i = 0; i < 4; i++) {
    int r = rb + 8 * i;
    float v = red[0][r][c] + red[1][r][c] + red[2][r][c] + red[3][r][c];
    v = fmaxf(v + bb, 0.f);
    if (g.store_bf16) ((bf16*)g.C)[(size_t)(mt + r) * HD + nt + c] = __hip_bfloat16(v);
    else              ((float*)g.C)[(size_t)(mt + r) * HD + nt + c] = v;
  }
}

// ---------------------------------------------------------------------------
// Heads: all 4 output projections (f32 weights/act), one row per block.
// grid 768: [0,128) ner N=10 | [128,384) rel N=8 | [384,512) emd N=2 | [512,768) cr N=1
// ---------------------------------------------------------------------------
__global__ __launch_bounds__(256) void k_heads(
    const float* __restrict__ NH, const float* __restrict__ EH,
    const float* __restrict__ RH2, const float* __restrict__ CH2,
    const float* __restrict__ nhw, const float* __restrict__ nhb,
    const float* __restrict__ ehw, const float* __restrict__ ehb,
    const float* __restrict__ rw3, const float* __restrict__ rb3,
    const float* __restrict__ cw3, const float* __restrict__ cb3,
    float* __restrict__ out)
{
  int gr = blockIdx.x;
  const float* A; const float* W; const float* Bb; float* op; int N;
  if (gr < 128)      { A = NH  + (size_t)gr * HD;        W = nhw; Bb = nhb; N = 10; op = out + (size_t)gr * 10; }
  else if (gr < 384) { int r = gr - 128; A = RH2 + (size_t)r * HD; W = rw3; Bb = rb3; N = 8; op = out + 1280 + (size_t)r * 8; }
  else if (gr < 512) { int r = gr - 384; A = EH  + (size_t)r * HD; W = ehw; Bb = ehb; N = 2; op = out + 3328 + (size_t)r * 2; }
  else               { int r = gr - 512; A = CH2 + (size_t)r * HD; W = cw3; Bb = cb3; N = 1; op = out + 3584 + (size_t)r; }

  float acc[10];
  #pragma unroll
  for (int o = 0; o < 10; o++) acc[o] = 0.f;

  for (int k = threadIdx.x; k < HD; k += 256) {
    float a = A[k];
    #pragma unroll
    for (int o = 0; o < 10; o++) {
      int oo = (o < N) ? o : 0;   // guard OOB weight reads; junk accs unused
      acc[o] += a * W[(size_t)oo * HD + k];
    }
  }

  __shared__ float red[4][10];
  int lane = threadIdx.x & 63, wv = threadIdx.x >> 6;
  #pragma unroll
  for (int o = 0; o < 10; o++) {
    float v = acc[o];
    for (int off = 32; off > 0; off >>= 1) v += __shfl_down(v, off);
    if (lane == 0) red[wv][o] = v;
  }
  __syncthreads();
  if (threadIdx.x < N) {
    float v = red[0][threadIdx.x] + red[1][threadIdx.x] + red[2][threadIdx.x] +
              red[3][threadIdx.x] + Bb[threadIdx.x];
    op[threadIdx.x] = v;
  }
}

// ---------------------------------------------------------------------------
extern "C" void kernel_launch(void* const* d_in, const int* in_sizes, int n_in,
                              void* d_out, int out_size, void* d_ws, size_t ws_size,
                              hipStream_t stream)
{
  const int*   input_ids  = (const int*)d_in[0];
  const int*   e_masks    = (const int*)d_in[1];
  const int*   e_sizes    = (const int*)d_in[2];
  const int*   m_masks    = (const int*)d_in[3];
  const int*   m_sizes    = (const int*)d_in[4];
  const int*   relations  = (const int*)d_in[5];
  const int*   r_masks    = (const int*)d_in[6];
  const int*   references = (const int*)d_in[7];
  const int*   c_masks    = (const int*)d_in[8];
  const float* emb        = (const float*)d_in[9];
  const float* nsemb      = (const float*)d_in[10];
  const float* esemb      = (const float*)d_in[11];
  const float* ner_rep_w  = (const float*)d_in[12];
  const float* ner_rep_b  = (const float*)d_in[13];
  const float* ner_head_w = (const float*)d_in[14];
  const float* ner_head_b = (const float*)d_in[15];
  const float* emd_rep_w  = (const float*)d_in[16];
  const float* emd_rep_b  = (const float*)d_in[17];
  const float* emd_head_w = (const float*)d_in[18];
  const float* emd_head_b = (const float*)d_in[19];
  const float* rel_w1 = (const float*)d_in[20];
  const float* rel_b1 = (const float*)d_in[21];
  const float* rel_w2 = (const float*)d_in[22];
  const float* rel_b2 = (const float*)d_in[23];
  const float* rel_w3 = (const float*)d_in[24];
  const float* rel_b3 = (const float*)d_in[25];
  const float* cr_w1 = (const float*)d_in[26];
  const float* cr_b1 = (const float*)d_in[27];
  const float* cr_w2 = (const float*)d_in[28];
  const float* cr_b2 = (const float*)d_in[29];
  const float* cr_w3 = (const float*)d_in[30];
  const float* cr_b3 = (const float*)d_in[31];
  float* out = (float*)d_out;

  // ---- workspace carve: f32/int region, then bf16 region ----
  float* wsf = (float*)d_ws;
  size_t o = 0;
  int*   FLAGS = (int*)(wsf + o); o += 8 * 768;
  float* NH  = wsf + o; o += (size_t)128 * HD;
  float* EH  = wsf + o; o += (size_t)128 * HD;
  float* RH2 = wsf + o; o += (size_t)256 * HD;
  float* CH2 = wsf + o; o += (size_t)256 * HD;

  bf16* wsb = (bf16*)(wsf + o);
  size_t ob = 0;
  bf16* WBF   = wsb + ob; ob += (size_t)W_TOT;          // 7225344
  bf16* PART  = wsb + ob; ob += (size_t)8 * 768 * HD;   // 4718592
  bf16* EPOOL = wsb + ob; ob += (size_t)128 * HD;
  bf16* MPOOL = wsb + ob; ob += (size_t)128 * HD;
  bf16* RCTX  = wsb + ob; ob += (size_t)256 * HD;
  bf16* CCTX  = wsb + ob; ob += (size_t)256 * HD;
  bf16* NREP  = wsb + ob; ob += (size_t)128 * 1568;
  bf16* EREP  = wsb + ob; ob += (size_t)128 * 1568;
  bf16* RREP  = wsb + ob; ob += (size_t)256 * 2368;
  bf16* CREP  = wsb + ob; ob += (size_t)256 * 2368;
  bf16* RH1   = wsb + ob; ob += (size_t)256 * HD;
  bf16* CH1   = wsb + ob; ob += (size_t)256 * HD;

  // 1) fused pooling partials + weight convert
  k_pool_cvt<<<768 + CVT_BLOCKS, 256, 0, stream>>>(
      e_masks, m_masks, r_masks, c_masks, emb, PART, FLAGS,
      ner_rep_w, emd_rep_w, rel_w1, cr_w1, rel_w2, cr_w2, WBF);
  // 2) combine splits -> bf16 pools/ctx
  k_combine<<<768, 256, 0, stream>>>(PART, FLAGS, EPOOL, MPOOL, RCTX, CCTX);
  // 3) rep builds (merged)
  k_rep<<<dim3(256, 4), 256, 0, stream>>>(input_ids, emb, EPOOL, MPOOL, RCTX, CCTX,
                                          e_sizes, m_sizes, nsemb, esemb,
                                          relations, references,
                                          NREP, EREP, RREP, CREP);
  // 4) GEMM layer 1: ner/emd (K=1568, M=128, f32 out) + rel/cr (K=2368, M=256, bf16 out)
  {
    GemmArgs4 ga;
    ga.p[0] = { NREP, WBF + WOFF_NER, ner_rep_b, NH,  1568, 128, 0 };
    ga.p[1] = { EREP, WBF + WOFF_EMD, emd_rep_b, EH,  1568, 128, 0 };
    ga.p[2] = { RREP, WBF + WOFF_RW1, rel_b1,    RH1, 2368, 256, 1 };
    ga.p[3] = { CREP, WBF + WOFF_CW1, cr_b1,     CH1, 2368, 256, 1 };
    k_gemm4<<<dim3(8, 24, 4), 256, 0, stream>>>(ga);
  }
  // 5) GEMM layer 2: rel2/cr2 (K=768, M=256, f32 out)
  {
    GemmArgs4 ga;
    ga.p[0] = { RH1, WBF + WOFF_RW2, rel_b2, RH2, 768, 256, 0 };
    ga.p[1] = { CH1, WBF + WOFF_CW2, cr_b2,  CH2, 768, 256, 0 };
    ga.p[2] = ga.p[0]; ga.p[3] = ga.p[1];   // unused (grid z=2)
    k_gemm4<<<dim3(8, 24, 2), 256, 0, stream>>>(ga);
  }
  // 6) heads -> d_out
  k_heads<<<768, 256, 0, stream>>>(NH, EH, RH2, CH2,
                                   ner_head_w, ner_head_b, emd_head_w, emd_head_b,
                                   rel_w3, rel_b3, cr_w3, cr_b3, out);
}